// Round 1
// baseline (774.942 us; speedup 1.0000x reference)
//
#include <hip/hip_runtime.h>
#include <math.h>

// Round 0: correct fp32 baseline for NonLocalBlockND.
// Layouts: Q[B][4096][32], K[B][1024][32] (phi), V[B][1024][32] (origin), all fp32 in ws.
// z[B][64][4096] = convW(attn(Q,K,V)) + bW + x.

#define B_SZ 16
#define C_IN 64
#define C_INT 32
#define HW 4096        // 64*64
#define NKV 1024       // 32*32
#define ROWS 8         // Q rows per attention block
#define CHUNK 128      // m-chunk staged in LDS
#define KVSTRIDE 36    // padded LDS row stride for K/V chunks (16B-aligned, breaks bank aliasing)
#define PSTRIDE 1032   // padded probs row stride (multiple of 4)

// ---------------- kernel 1: theta conv (full res) -> Q ----------------
__global__ __launch_bounds__(256) void k_theta(
    const float* __restrict__ x, const float* __restrict__ w,
    const float* __restrict__ bias, float* __restrict__ Q) {
  __shared__ __align__(16) float ws[C_INT * C_IN];
  __shared__ float bs[C_INT];
  int t = threadIdx.x;
  for (int i = t; i < C_INT * C_IN; i += 256) ws[i] = w[i];
  if (t < C_INT) bs[t] = bias[t];
  __syncthreads();
  int gid = blockIdx.x * 256 + t;        // over 16*4096
  int bb = gid >> 12;
  int p  = gid & 4095;
  const float* xp = x + ((size_t)bb << 18) + p;
  float acc[C_INT];
  #pragma unroll
  for (int o = 0; o < C_INT; ++o) acc[o] = bs[o];
  for (int cq = 0; cq < 16; ++cq) {
    float xv0 = xp[(size_t)(4*cq+0) << 12];
    float xv1 = xp[(size_t)(4*cq+1) << 12];
    float xv2 = xp[(size_t)(4*cq+2) << 12];
    float xv3 = xp[(size_t)(4*cq+3) << 12];
    #pragma unroll
    for (int o = 0; o < C_INT; ++o) {
      const float4 w4 = *(const float4*)&ws[o * C_IN + 4*cq];
      acc[o] += xv0*w4.x + xv1*w4.y + xv2*w4.z + xv3*w4.w;
    }
  }
  float4* qp = (float4*)(Q + (size_t)gid * C_INT);
  #pragma unroll
  for (int oq = 0; oq < C_INT/4; ++oq)
    qp[oq] = make_float4(acc[4*oq], acc[4*oq+1], acc[4*oq+2], acc[4*oq+3]);
}

// -------- kernel 2: phi & origin conv + 2x2 maxpool -> K, V --------
// Thread = (pooled position, source-pixel d). Max-reduce over d via LDS.
__global__ __launch_bounds__(256) void k_kv(
    const float* __restrict__ x,
    const float* __restrict__ wphi, const float* __restrict__ bphi,
    const float* __restrict__ worg, const float* __restrict__ borg,
    float* __restrict__ K, float* __restrict__ V) {
  __shared__ __align__(16) float ws[2 * C_INT * C_IN];  // phi | origin
  __shared__ float bs[2 * C_INT];
  __shared__ float red[4 * 64 * 33];                    // [d][mp_off][o], padded
  int t = threadIdx.x;
  for (int i = t; i < C_INT * C_IN; i += 256) {
    ws[i] = wphi[i];
    ws[C_INT * C_IN + i] = worg[i];
  }
  if (t < C_INT) { bs[t] = bphi[t]; bs[C_INT + t] = borg[t]; }
  int bb = blockIdx.x >> 4;        // batch
  int g  = blockIdx.x & 15;        // group of 64 pooled positions
  int mp_off = t & 63;
  int d = t >> 6;                  // which of the 4 pooled source pixels
  int mp = g * 64 + mp_off;
  int py = mp >> 5, px = mp & 31;
  int pix = (py << 7) + (px << 1) + ((d >> 1) << 6) + (d & 1);
  const float* xp = x + ((size_t)bb << 18) + pix;
  __syncthreads();
  for (int sel = 0; sel < 2; ++sel) {
    float acc[C_INT];
    #pragma unroll
    for (int o = 0; o < C_INT; ++o) acc[o] = bs[sel * C_INT + o];
    for (int cq = 0; cq < 16; ++cq) {
      float xv0 = xp[(size_t)(4*cq+0) << 12];
      float xv1 = xp[(size_t)(4*cq+1) << 12];
      float xv2 = xp[(size_t)(4*cq+2) << 12];
      float xv3 = xp[(size_t)(4*cq+3) << 12];
      #pragma unroll
      for (int o = 0; o < C_INT; ++o) {
        const float4 w4 = *(const float4*)&ws[sel * C_INT * C_IN + o * C_IN + 4*cq];
        acc[o] += xv0*w4.x + xv1*w4.y + xv2*w4.z + xv3*w4.w;
      }
    }
    #pragma unroll
    for (int o = 0; o < C_INT; ++o) red[(d * 64 + mp_off) * 33 + o] = acc[o];
    __syncthreads();
    float* dst = (sel == 0 ? K : V);
    #pragma unroll
    for (int k = 0; k < 8; ++k) {
      int flat = k * 256 + t;               // 0..2047 = 64 mp * 32 o
      int mo = flat >> 5, o = flat & 31;
      float v0 = red[(0 * 64 + mo) * 33 + o];
      float v1 = red[(1 * 64 + mo) * 33 + o];
      float v2 = red[(2 * 64 + mo) * 33 + o];
      float v3 = red[(3 * 64 + mo) * 33 + o];
      dst[((size_t)bb * NKV + (size_t)g * 64 + mo) * C_INT + o] =
          fmaxf(fmaxf(v0, v1), fmaxf(v2, v3));
    }
    __syncthreads();
  }
}

// -------- kernel 3: attention + output conv + residual --------
// Block: 256 threads = 8 rows x 32 lanes. Exact softmax over full Nkv=1024.
__global__ __launch_bounds__(256) void k_attn(
    const float* __restrict__ Q, const float* __restrict__ K, const float* __restrict__ V,
    const float* __restrict__ x, const float* __restrict__ wW, const float* __restrict__ bW,
    float* __restrict__ z) {
  __shared__ __align__(16) float sq[ROWS * C_INT];
  __shared__ __align__(16) float kv[CHUNK * KVSTRIDE];
  __shared__ __align__(16) float probs[ROWS * PSTRIDE];
  __shared__ __align__(16) float sy[ROWS * C_INT];
  __shared__ __align__(16) float swW[C_IN * C_INT];
  __shared__ float sbW[C_IN];

  int t = threadIdx.x;
  int bb   = blockIdx.x >> 9;
  int tile = blockIdx.x & 511;
  int p0 = tile * ROWS;
  int r = t >> 5;      // row 0..7
  int j = t & 31;      // lane-in-row 0..31

  for (int i = t; i < C_IN * C_INT; i += 256) swW[i] = wW[i];
  if (t < C_IN) sbW[t] = bW[t];
  sq[t] = Q[((size_t)(bb << 12) + p0) * C_INT + t];   // 256 floats = ROWS*C_INT
  __syncthreads();

  float qreg[C_INT];
  #pragma unroll
  for (int c = 0; c < C_INT; ++c) qreg[c] = sq[r * C_INT + c];

  // ---- scores: S[r][m] for all m, kept in registers (32 per thread)
  float sreg[32];
  const float4* Kg4 = (const float4*)(K + (size_t)bb * NKV * C_INT);
  for (int ch = 0; ch < NKV / CHUNK; ++ch) {
    __syncthreads();
    #pragma unroll
    for (int k = 0; k < 4; ++k) {
      int idx = k * 256 + t;            // 0..1023 float4s of the chunk
      int m = idx >> 3, cq = idx & 7;
      float4 f = Kg4[ch * (CHUNK * C_INT / 4) + idx];
      *(float4*)&kv[m * KVSTRIDE + cq * 4] = f;
    }
    __syncthreads();
    #pragma unroll
    for (int mm = 0; mm < 4; ++mm) {
      int ml = mm * 32 + j;
      float s = 0.f;
      #pragma unroll
      for (int cq = 0; cq < 8; ++cq) {
        const float4 kf = *(const float4*)&kv[ml * KVSTRIDE + cq * 4];
        s += qreg[4*cq+0]*kf.x + qreg[4*cq+1]*kf.y + qreg[4*cq+2]*kf.z + qreg[4*cq+3]*kf.w;
      }
      sreg[ch * 4 + mm] = s;
    }
  }

  // ---- softmax per row (32 lanes per row, intra-wave shuffle reduce)
  float mymax = -1e30f;
  #pragma unroll
  for (int i = 0; i < 32; ++i) mymax = fmaxf(mymax, sreg[i]);
  #pragma unroll
  for (int off = 16; off >= 1; off >>= 1) mymax = fmaxf(mymax, __shfl_xor(mymax, off));
  float sum = 0.f;
  #pragma unroll
  for (int i = 0; i < 32; ++i) { float e = __expf(sreg[i] - mymax); sreg[i] = e; sum += e; }
  #pragma unroll
  for (int off = 16; off >= 1; off >>= 1) sum += __shfl_xor(sum, off);
  float inv = 1.f / sum;
  #pragma unroll
  for (int i = 0; i < 32; ++i) {
    int m = (i >> 2) * 128 + (i & 3) * 32 + j;
    probs[r * PSTRIDE + m] = sreg[i] * inv;
  }

  // ---- y = P @ V   (thread owns channel j of row r)
  float accy = 0.f;
  const float4* Vg4 = (const float4*)(V + (size_t)bb * NKV * C_INT);
  for (int ch = 0; ch < NKV / CHUNK; ++ch) {
    __syncthreads();
    #pragma unroll
    for (int k = 0; k < 4; ++k) {
      int idx = k * 256 + t;
      int m = idx >> 3, cq = idx & 7;
      float4 f = Vg4[ch * (CHUNK * C_INT / 4) + idx];
      *(float4*)&kv[m * KVSTRIDE + cq * 4] = f;
    }
    __syncthreads();
    #pragma unroll
    for (int mq = 0; mq < 32; ++mq) {
      const float4 pv = *(const float4*)&probs[r * PSTRIDE + ch * CHUNK + mq * 4];
      accy += pv.x * kv[(mq*4+0) * KVSTRIDE + j];
      accy += pv.y * kv[(mq*4+1) * KVSTRIDE + j];
      accy += pv.z * kv[(mq*4+2) * KVSTRIDE + j];
      accy += pv.w * kv[(mq*4+3) * KVSTRIDE + j];
    }
  }
  sy[r * C_INT + j] = accy;
  __syncthreads();

  // ---- z = convW(y) + bW + x  (fused epilogue)
  int r2 = t & 7;
  int co = t >> 3;     // 0..31, handles co and co+32
  #pragma unroll
  for (int half = 0; half < 2; ++half) {
    int c_out = co + half * 32;
    size_t zi = ((size_t)bb << 18) + ((size_t)c_out << 12) + p0 + r2;
    float acc = sbW[c_out] + x[zi];
    #pragma unroll
    for (int ci = 0; ci < C_INT; ++ci)
      acc += sy[r2 * C_INT + ci] * swW[c_out * C_INT + ci];
    z[zi] = acc;
  }
}

extern "C" void kernel_launch(void* const* d_in, const int* in_sizes, int n_in,
                              void* d_out, int out_size, void* d_ws, size_t ws_size,
                              hipStream_t stream) {
  const float* x   = (const float*)d_in[0];
  const float* w_o = (const float*)d_in[1];
  const float* b_o = (const float*)d_in[2];
  const float* w_t = (const float*)d_in[3];
  const float* b_t = (const float*)d_in[4];
  const float* w_p = (const float*)d_in[5];
  const float* b_p = (const float*)d_in[6];
  const float* w_W = (const float*)d_in[7];
  const float* b_W = (const float*)d_in[8];
  float* z = (float*)d_out;

  float* Q = (float*)d_ws;                                  // 16*4096*32
  float* K = Q + (size_t)B_SZ * HW * C_INT;                 // 16*1024*32
  float* V = K + (size_t)B_SZ * NKV * C_INT;                // 16*1024*32

  k_theta<<<dim3((B_SZ * HW) / 256), dim3(256), 0, stream>>>(x, w_t, b_t, Q);
  k_kv<<<dim3((B_SZ * NKV * 4) / 256), dim3(256), 0, stream>>>(x, w_p, b_p, w_o, b_o, K, V);
  k_attn<<<dim3(B_SZ * (HW / ROWS)), dim3(256), 0, stream>>>(Q, K, V, x, w_W, b_W, z);
}

// Round 2
// 155.898 us; speedup vs baseline: 4.9708x; 4.9708x over previous
//
#include <hip/hip_runtime.h>
#include <hip/hip_bf16.h>
#include <math.h>

// Round 2: bf16-MFMA flash attention (no-max softmax, hi/lo-split scores),
// fused W-conv + residual epilogue. Prep convs split for 2x thread parallelism.
// Layouts: Qhi/Qlo [B][4096][32] bf16, Khi/Klo [B][1024][32] bf16,
//          Vt [B][32][1024] bf16 (channel-major for PV B-frags).

#define B_SZ 16
#define C_IN 64
#define C_INT 32
#define HW 4096
#define NKV 1024
#define CHK 128      // KV cols per chunk
#define NCHUNK 8
#define KSTR 40      // sK row stride (ushorts): 2-way-only bank aliasing
#define VSTR 136     // sVt / sP row stride (ushorts): 2-way-only

typedef __attribute__((ext_vector_type(8))) short bfrag;
typedef __attribute__((ext_vector_type(4))) float f32x4;

static __device__ __forceinline__ ushort f2bf(float v) {
  union { float f; uint u; } c; c.f = v;
  uint b = c.u + 0x7FFFu + ((c.u >> 16) & 1u);   // round-to-nearest-even
  return (ushort)(b >> 16);
}
static __device__ __forceinline__ float bf2f(ushort h) {
  union { uint u; float f; } c; c.u = (uint)h << 16; return c.f;
}

// ---------------- kernel 1: theta conv -> Qhi/Qlo ----------------
__global__ __launch_bounds__(256) void k_theta(
    const float* __restrict__ x, const float* __restrict__ w,
    const float* __restrict__ bias, ushort* __restrict__ Qhi, ushort* __restrict__ Qlo) {
  __shared__ __align__(16) float ws[C_INT * C_IN];
  __shared__ float bs[C_INT];
  int t = threadIdx.x;
  for (int i = t; i < C_INT * C_IN; i += 256) ws[i] = w[i];
  if (t < C_INT) bs[t] = bias[t];
  __syncthreads();
  int gid  = blockIdx.x * 128 + (t & 127);   // pixel id over 16*4096
  int half = t >> 7;                          // 16 out-channels each
  int bb = gid >> 12;
  int p  = gid & 4095;
  const float* xp = x + ((size_t)bb << 18) + p;
  float acc[16];
  #pragma unroll
  for (int o = 0; o < 16; ++o) acc[o] = bs[half * 16 + o];
  for (int cq = 0; cq < 16; ++cq) {
    float xv0 = xp[(size_t)(4*cq+0) << 12];
    float xv1 = xp[(size_t)(4*cq+1) << 12];
    float xv2 = xp[(size_t)(4*cq+2) << 12];
    float xv3 = xp[(size_t)(4*cq+3) << 12];
    #pragma unroll
    for (int o = 0; o < 16; ++o) {
      const float4 w4 = *(const float4*)&ws[(half*16+o) * C_IN + 4*cq];
      acc[o] += xv0*w4.x + xv1*w4.y + xv2*w4.z + xv3*w4.w;
    }
  }
  union { ushort u[16]; uint4 v[2]; } H, L;
  #pragma unroll
  for (int o = 0; o < 16; ++o) {
    ushort hb = f2bf(acc[o]);
    H.u[o] = hb;
    L.u[o] = f2bf(acc[o] - bf2f(hb));
  }
  uint4* qh = (uint4*)(Qhi + (size_t)gid * 32 + half * 16);
  qh[0] = H.v[0]; qh[1] = H.v[1];
  uint4* ql = (uint4*)(Qlo + (size_t)gid * 32 + half * 16);
  ql[0] = L.v[0]; ql[1] = L.v[1];
}

// -------- kernel 2: phi & origin conv + maxpool -> Khi/Klo, Vt --------
__global__ __launch_bounds__(256) void k_kv(
    const float* __restrict__ x,
    const float* __restrict__ wphi, const float* __restrict__ bphi,
    const float* __restrict__ worg, const float* __restrict__ borg,
    ushort* __restrict__ Khi, ushort* __restrict__ Klo, ushort* __restrict__ Vt) {
  __shared__ __align__(16) float ws[2 * C_INT * C_IN];  // phi | origin
  __shared__ float bs[2 * C_INT];
  __shared__ float red[2][4][32][33];
  int t = threadIdx.x;
  for (int i = t; i < C_INT * C_IN; i += 256) {
    ws[i] = wphi[i];
    ws[C_INT * C_IN + i] = worg[i];
  }
  if (t < C_INT) { bs[t] = bphi[t]; bs[C_INT + t] = borg[t]; }
  int bb  = blockIdx.x >> 5;
  int g   = blockIdx.x & 31;       // 32 groups of 32 pooled positions
  int sel = t >> 7;                // 0: phi(K), 1: origin(V)
  int sub = t & 127;
  int d = sub >> 5;
  int mp_off = sub & 31;
  int mp = g * 32 + mp_off;
  int py = mp >> 5, px = mp & 31;
  int pix = (py << 7) + (px << 1) + ((d >> 1) << 6) + (d & 1);
  const float* xp = x + ((size_t)bb << 18) + pix;
  __syncthreads();
  float acc[C_INT];
  #pragma unroll
  for (int o = 0; o < C_INT; ++o) acc[o] = bs[sel * C_INT + o];
  for (int cq = 0; cq < 16; ++cq) {
    float xv0 = xp[(size_t)(4*cq+0) << 12];
    float xv1 = xp[(size_t)(4*cq+1) << 12];
    float xv2 = xp[(size_t)(4*cq+2) << 12];
    float xv3 = xp[(size_t)(4*cq+3) << 12];
    #pragma unroll
    for (int o = 0; o < C_INT; ++o) {
      const float4 w4 = *(const float4*)&ws[sel * C_INT * C_IN + o * C_IN + 4*cq];
      acc[o] += xv0*w4.x + xv1*w4.y + xv2*w4.z + xv3*w4.w;
    }
  }
  #pragma unroll
  for (int o = 0; o < C_INT; ++o) red[sel][d][mp_off][o] = acc[o];
  __syncthreads();
  if (sel == 0) {
    for (int f = sub; f < 1024; f += 128) {
      int mo = f >> 5, o = f & 31;
      float v = fmaxf(fmaxf(red[0][0][mo][o], red[0][1][mo][o]),
                      fmaxf(red[0][2][mo][o], red[0][3][mo][o]));
      ushort hb = f2bf(v);
      size_t idx = ((size_t)bb * NKV + g * 32 + mo) * 32 + o;
      Khi[idx] = hb;
      Klo[idx] = f2bf(v - bf2f(hb));
    }
  } else {
    for (int f = sub; f < 1024; f += 128) {
      int o = f >> 5, mo = f & 31;
      float v = fmaxf(fmaxf(red[1][0][mo][o], red[1][1][mo][o]),
                      fmaxf(red[1][2][mo][o], red[1][3][mo][o]));
      Vt[((size_t)bb * 32 + o) * NKV + g * 32 + mo] = f2bf(v);
    }
  }
}

// -------- kernel 3: MFMA flash attention + W-conv + residual --------
// 256 threads = 4 waves; wave owns 32 Q-rows (2 row-tiles); block = 128 rows.
__global__ __launch_bounds__(256) void k_attn(
    const ushort* __restrict__ Qhi, const ushort* __restrict__ Qlo,
    const ushort* __restrict__ Khi, const ushort* __restrict__ Klo,
    const ushort* __restrict__ Vt,
    const float* __restrict__ x, const float* __restrict__ wW,
    const float* __restrict__ bW, float* __restrict__ z) {
  __shared__ __align__(16) ushort sKhi[128 * KSTR];
  __shared__ __align__(16) ushort sKlo[128 * KSTR];
  __shared__ __align__(16) ushort sVt[32 * VSTR];
  __shared__ __align__(16) ushort sP[4][32 * VSTR];   // per-wave P buffers
  __shared__ __align__(16) float sW[C_IN * C_INT];
  __shared__ float sbW[C_IN];

  int t = threadIdx.x;
  int wave = t >> 6, lane = t & 63, l15 = lane & 15, quad = lane >> 4;
  int bb = blockIdx.x >> 5;
  int p0 = (blockIdx.x & 31) << 7;   // 128 rows per block
  int wp0 = p0 + wave * 32;

  for (int i = t; i < C_IN * C_INT; i += 256) sW[i] = wW[i];
  if (t < C_IN) sbW[t] = bW[t];

  // Q A-frags (A[m=lane&15][k=quad*8+j]) -- resident all kernel
  bfrag aQh[2], aQl[2];
  #pragma unroll
  for (int rt = 0; rt < 2; ++rt) {
    size_t base = ((size_t)bb * HW + wp0 + rt * 16 + l15) * 32 + quad * 8;
    aQh[rt] = *(const bfrag*)(Qhi + base);
    aQl[rt] = *(const bfrag*)(Qlo + base);
  }

  f32x4 accO[2][2];
  #pragma unroll
  for (int i = 0; i < 2; ++i)
    #pragma unroll
    for (int j = 0; j < 2; ++j) accO[i][j] = (f32x4){0.f, 0.f, 0.f, 0.f};
  float lsum[8] = {0.f,0.f,0.f,0.f,0.f,0.f,0.f,0.f};

  const ushort* Kh_g = Khi + (size_t)bb * NKV * 32;
  const ushort* Kl_g = Klo + (size_t)bb * NKV * 32;
  const ushort* Vt_g = Vt  + (size_t)bb * 32 * NKV;
  ushort* myP = sP[wave];

  for (int c = 0; c < NCHUNK; ++c) {
    int k0 = c * CHK;
    __syncthreads();
    // ---- stage K (hi/lo) and Vt chunk
    #pragma unroll
    for (int i = 0; i < 2; ++i) {
      int idx = i * 256 + t;                 // 0..511 uint4s each
      int row = idx >> 2, seg = idx & 3;     // K: 128 rows x 32ch
      *(uint4*)&sKhi[row * KSTR + seg * 8] =
          *(const uint4*)(Kh_g + (size_t)(k0 + row) * 32 + seg * 8);
      *(uint4*)&sKlo[row * KSTR + seg * 8] =
          *(const uint4*)(Kl_g + (size_t)(k0 + row) * 32 + seg * 8);
      int vrow = idx >> 4, vseg = idx & 15;  // Vt: 32 rows x 128 cols
      *(uint4*)&sVt[vrow * VSTR + vseg * 8] =
          *(const uint4*)(Vt_g + (size_t)vrow * NKV + k0 + vseg * 8);
    }
    __syncthreads();

    // ---- S = Q.K^T  (hi*hi + lo*hi + hi*lo; lo*lo ~ 2^-18, dropped)
    f32x4 S[2][8];
    #pragma unroll
    for (int tt = 0; tt < 8; ++tt) {
      bfrag bh = *(const bfrag*)&sKhi[(tt * 16 + l15) * KSTR + quad * 8];
      bfrag bl = *(const bfrag*)&sKlo[(tt * 16 + l15) * KSTR + quad * 8];
      #pragma unroll
      for (int rt = 0; rt < 2; ++rt) {
        f32x4 a = (f32x4){0.f, 0.f, 0.f, 0.f};
        a = __builtin_amdgcn_mfma_f32_16x16x32_bf16(aQh[rt], bh, a, 0, 0, 0);
        a = __builtin_amdgcn_mfma_f32_16x16x32_bf16(aQl[rt], bh, a, 0, 0, 0);
        a = __builtin_amdgcn_mfma_f32_16x16x32_bf16(aQh[rt], bl, a, 0, 0, 0);
        S[rt][tt] = a;
      }
    }

    // ---- exp (no max-sub: fp32 range is ample), row-sum, P -> LDS (bf16)
    #pragma unroll
    for (int rt = 0; rt < 2; ++rt)
      #pragma unroll
      for (int tt = 0; tt < 8; ++tt)
        #pragma unroll
        for (int r = 0; r < 4; ++r) {
          float e = __expf(S[rt][tt][r]);
          lsum[rt * 4 + r] += e;
          myP[(rt * 16 + quad * 4 + r) * VSTR + tt * 16 + l15] = f2bf(e);
        }

    // ---- O += P.V  (per-wave P buffer: no barrier, only lgkmcnt wait)
    #pragma unroll
    for (int ks = 0; ks < 4; ++ks) {
      bfrag a0 = *(const bfrag*)&myP[(0 * 16 + l15) * VSTR + ks * 32 + quad * 8];
      bfrag a1 = *(const bfrag*)&myP[(1 * 16 + l15) * VSTR + ks * 32 + quad * 8];
      bfrag b0 = *(const bfrag*)&sVt[(0 * 16 + l15) * VSTR + ks * 32 + quad * 8];
      bfrag b1 = *(const bfrag*)&sVt[(1 * 16 + l15) * VSTR + ks * 32 + quad * 8];
      accO[0][0] = __builtin_amdgcn_mfma_f32_16x16x32_bf16(a0, b0, accO[0][0], 0, 0, 0);
      accO[0][1] = __builtin_amdgcn_mfma_f32_16x16x32_bf16(a0, b1, accO[0][1], 0, 0, 0);
      accO[1][0] = __builtin_amdgcn_mfma_f32_16x16x32_bf16(a1, b0, accO[1][0], 0, 0, 0);
      accO[1][1] = __builtin_amdgcn_mfma_f32_16x16x32_bf16(a1, b1, accO[1][1], 0, 0, 0);
    }
  }

  // ---- finalize softmax: reduce row sums across the 16 lanes of each quad
  #pragma unroll
  for (int off = 1; off < 16; off <<= 1)
    #pragma unroll
    for (int i = 0; i < 8; ++i) lsum[i] += __shfl_xor(lsum[i], off);
  float inv[8];
  #pragma unroll
  for (int i = 0; i < 8; ++i) inv[i] = 1.0f / lsum[i];

  __syncthreads();                       // all waves done with sP / sVt
  float* sy = (float*)&sP[0][0];         // reuse as y[128][33]
  #pragma unroll
  for (int rt = 0; rt < 2; ++rt)
    #pragma unroll
    for (int n = 0; n < 2; ++n)
      #pragma unroll
      for (int r = 0; r < 4; ++r)
        sy[(wave * 32 + rt * 16 + quad * 4 + r) * 33 + n * 16 + l15] =
            accO[rt][n][r] * inv[rt * 4 + r];
  __syncthreads();

  // ---- z = W.y + bW + x
  int pl = t & 127, halfo = t >> 7;
  float yv[C_INT];
  #pragma unroll
  for (int ci = 0; ci < C_INT; ++ci) yv[ci] = sy[pl * 33 + ci];
  #pragma unroll
  for (int co = 0; co < 32; ++co) {
    int cout = halfo * 32 + co;
    size_t zi = ((size_t)bb << 18) + ((size_t)cout << 12) + p0 + pl;
    float a = sbW[cout] + x[zi];
    #pragma unroll
    for (int ci = 0; ci < C_INT; ++ci) a += yv[ci] * sW[cout * C_INT + ci];
    z[zi] = a;
  }
}

extern "C" void kernel_launch(void* const* d_in, const int* in_sizes, int n_in,
                              void* d_out, int out_size, void* d_ws, size_t ws_size,
                              hipStream_t stream) {
  const float* x   = (const float*)d_in[0];
  const float* w_o = (const float*)d_in[1];
  const float* b_o = (const float*)d_in[2];
  const float* w_t = (const float*)d_in[3];
  const float* b_t = (const float*)d_in[4];
  const float* w_p = (const float*)d_in[5];
  const float* b_p = (const float*)d_in[6];
  const float* w_W = (const float*)d_in[7];
  const float* b_W = (const float*)d_in[8];
  float* z = (float*)d_out;

  ushort* Qhi = (ushort*)d_ws;                              // 16*4096*32
  ushort* Qlo = Qhi + (size_t)B_SZ * HW * C_INT;
  ushort* Khi = Qlo + (size_t)B_SZ * HW * C_INT;            // 16*1024*32
  ushort* Klo = Khi + (size_t)B_SZ * NKV * C_INT;
  ushort* Vtw = Klo + (size_t)B_SZ * NKV * C_INT;           // 16*32*1024

  k_theta<<<dim3((B_SZ * HW) / 128), dim3(256), 0, stream>>>(x, w_t, b_t, Qhi, Qlo);
  k_kv<<<dim3(B_SZ * 32), dim3(256), 0, stream>>>(x, w_p, b_p, w_o, b_o, Khi, Klo, Vtw);
  k_attn<<<dim3(B_SZ * 32), dim3(256), 0, stream>>>(Qhi, Qlo, Khi, Klo, Vtw, x, w_W, b_W, z);
}